// Round 1
// baseline (512.445 us; speedup 1.0000x reference)
//
#include <hip/hip_runtime.h>
#include <math.h>

// CosFace-style loss:
//   num_i   = S*(x[i,y_i] - M)
//   sum_i   = sum_j exp(S*x[i,j])
//   denom_i = exp(num_i) + (sum_i - exp(S*x[i,y_i]))
//   L_i     = (num_i - log(denom_i)) / S
//   out     = -mean_i(L_i)
// Memory-bound: 400 MB read of x, roofline ~64 us @ 6.3 TB/s.
// R1 change: 256 -> 512 threads/block (16 -> 32 waves/CU) to cover HBM latency.

#define SCALE 64.0f
#define MARGIN 0.35f
#define NT 512  // threads per block (8 waves)

__device__ __forceinline__ double block_reduce_d(double v) {
    // wave64 butterfly-down, then cross-wave via LDS (NT threads = NT/64 waves)
    #pragma unroll
    for (int off = 32; off > 0; off >>= 1) v += __shfl_down(v, off, 64);
    __shared__ double s[NT / 64];
    const int lane = threadIdx.x & 63;
    const int w    = threadIdx.x >> 6;
    if (lane == 0) s[w] = v;
    __syncthreads();
    if (w == 0) {
        v = (lane < NT / 64) ? s[lane] : 0.0;
        #pragma unroll
        for (int off = NT / 128; off > 0; off >>= 1) v += __shfl_down(v, off, 64);
    }
    return v;  // valid in thread 0
}

__global__ __launch_bounds__(NT) void row_loss_kernel(
    const float* __restrict__ x, const int* __restrict__ label,
    double* __restrict__ row_L, int C)
{
    const int row = blockIdx.x;
    const float* __restrict__ xr = x + (size_t)row * (size_t)C;
    const int tid = threadIdx.x;

    const int n4 = C >> 2;
    const float4* __restrict__ x4 = (const float4*)xr;

    double acc = 0.0;
    int v = tid;
    // unrolled x4: 4 independent float4 loads in flight per wave
    for (; v + 3 * NT < n4; v += 4 * NT) {
        float4 a = x4[v];
        float4 b = x4[v + NT];
        float4 c = x4[v + 2 * NT];
        float4 d = x4[v + 3 * NT];
        float s0 = __expf(SCALE * a.x) + __expf(SCALE * a.y) +
                   __expf(SCALE * a.z) + __expf(SCALE * a.w);
        float s1 = __expf(SCALE * b.x) + __expf(SCALE * b.y) +
                   __expf(SCALE * b.z) + __expf(SCALE * b.w);
        float s2 = __expf(SCALE * c.x) + __expf(SCALE * c.y) +
                   __expf(SCALE * c.z) + __expf(SCALE * c.w);
        float s3 = __expf(SCALE * d.x) + __expf(SCALE * d.y) +
                   __expf(SCALE * d.z) + __expf(SCALE * d.w);
        acc += (double)(s0 + s1) + (double)(s2 + s3);
    }
    for (; v < n4; v += NT) {
        float4 a = x4[v];
        float s0 = __expf(SCALE * a.x) + __expf(SCALE * a.y) +
                   __expf(SCALE * a.z) + __expf(SCALE * a.w);
        acc += (double)s0;
    }
    // scalar tail if C % 4 != 0
    for (int j = (n4 << 2) + tid; j < C; j += NT)
        acc += (double)__expf(SCALE * xr[j]);

    double row_sum = block_reduce_d(acc);

    if (tid == 0) {
        const double xy  = (double)xr[label[row]];
        const double num = 64.0 * (xy - 0.35);
        const double exy = exp(64.0 * xy);
        const double sum_excl = row_sum - exy;     // fp64: cancellation-safe
        const double denom = exp(num) + sum_excl;
        const double L = (num - log(denom)) / 64.0;
        row_L[row] = L;
    }
}

__global__ __launch_bounds__(NT) void final_reduce_kernel(
    const double* __restrict__ row_L, float* __restrict__ out, int B)
{
    double acc = 0.0;
    for (int i = threadIdx.x; i < B; i += NT) acc += row_L[i];
    double total = block_reduce_d(acc);
    if (threadIdx.x == 0) out[0] = (float)(-total / (double)B);
}

extern "C" void kernel_launch(void* const* d_in, const int* in_sizes, int n_in,
                              void* d_out, int out_size, void* d_ws, size_t ws_size,
                              hipStream_t stream) {
    const float* x     = (const float*)d_in[0];
    const int*   label = (const int*)d_in[1];
    const int B = in_sizes[1];
    const int C = in_sizes[0] / B;

    double* row_L = (double*)d_ws;  // B doubles = 8 KB scratch

    row_loss_kernel<<<B, NT, 0, stream>>>(x, label, row_L, C);
    final_reduce_kernel<<<1, NT, 0, stream>>>(row_L, (float*)d_out, B);
}

// Round 2
// 499.416 us; speedup vs baseline: 1.0261x; 1.0261x over previous
//
#include <hip/hip_runtime.h>
#include <math.h>

// CosFace-style loss:
//   num_i   = S*(x[i,y_i] - M)
//   sum_i   = sum_j exp(S*x[i,j])
//   denom_i = exp(num_i) + (sum_i - exp(S*x[i,y_i]))
//   L_i     = (num_i - log(denom_i)) / S
//   out     = -mean_i(L_i)
// Memory-bound: 409.6 MB read of x, roofline ~65 us @ 6.3 TB/s.
// R2 change: split each row across GSPLIT blocks (shorter per-block critical
// path, 4096 blocks), nontemporal streaming loads, separate finalize kernel.

#define SCALE 64.0f
#define MARGIN 0.35f
#define NT 256     // threads per block in partial-sum kernel (4 waves)
#define GSPLIT 4   // blocks per row

typedef float v4f __attribute__((ext_vector_type(4)));

template <int NWAVES>
__device__ __forceinline__ double block_reduce_d(double v) {
    #pragma unroll
    for (int off = 32; off > 0; off >>= 1) v += __shfl_down(v, off, 64);
    __shared__ double s[NWAVES];
    const int lane = threadIdx.x & 63;
    const int w    = threadIdx.x >> 6;
    if (lane == 0) s[w] = v;
    __syncthreads();
    if (w == 0) {
        v = (lane < NWAVES) ? s[lane] : 0.0;
        #pragma unroll
        for (int off = NWAVES / 2; off > 0; off >>= 1) v += __shfl_down(v, off, 64);
    }
    return v;  // valid in thread 0
}

// Each block computes sum_j exp(S*x[row, j]) over one 1/GSPLIT chunk of a row.
__global__ __launch_bounds__(NT) void partial_sum_kernel(
    const float* __restrict__ x, double* __restrict__ partials, int C)
{
    const int g   = blockIdx.x;   // chunk within row
    const int row = blockIdx.y;
    const float* __restrict__ xr = x + (size_t)row * (size_t)C;
    const int tid = threadIdx.x;

    const int n4    = C >> 2;
    const int begin = (int)(((long long)n4 * g) / GSPLIT);
    const int end   = (int)(((long long)n4 * (g + 1)) / GSPLIT);
    const v4f* __restrict__ x4 = (const v4f*)xr;

    double acc = 0.0;
    int v = begin + tid;
    // 4 independent nontemporal float4 loads in flight per thread
    for (; v + 3 * NT < end; v += 4 * NT) {
        v4f a = __builtin_nontemporal_load(x4 + v);
        v4f b = __builtin_nontemporal_load(x4 + v + NT);
        v4f c = __builtin_nontemporal_load(x4 + v + 2 * NT);
        v4f d = __builtin_nontemporal_load(x4 + v + 3 * NT);
        float s0 = __expf(SCALE * a.x) + __expf(SCALE * a.y) +
                   __expf(SCALE * a.z) + __expf(SCALE * a.w);
        float s1 = __expf(SCALE * b.x) + __expf(SCALE * b.y) +
                   __expf(SCALE * b.z) + __expf(SCALE * b.w);
        float s2 = __expf(SCALE * c.x) + __expf(SCALE * c.y) +
                   __expf(SCALE * c.z) + __expf(SCALE * c.w);
        float s3 = __expf(SCALE * d.x) + __expf(SCALE * d.y) +
                   __expf(SCALE * d.z) + __expf(SCALE * d.w);
        acc += (double)(s0 + s1) + (double)(s2 + s3);
    }
    for (; v < end; v += NT) {
        v4f a = __builtin_nontemporal_load(x4 + v);
        acc += (double)(__expf(SCALE * a.x) + __expf(SCALE * a.y) +
                        __expf(SCALE * a.z) + __expf(SCALE * a.w));
    }
    // scalar tail if C % 4 != 0 (handled by last chunk only)
    if (g == GSPLIT - 1) {
        for (int j = (n4 << 2) + tid; j < C; j += NT)
            acc += (double)__expf(SCALE * xr[j]);
    }

    double s = block_reduce_d<NT / 64>(acc);
    if (tid == 0) partials[(size_t)row * GSPLIT + g] = s;
}

// One block: combine per-row partials, apply margin epilogue, reduce mean.
__global__ __launch_bounds__(1024) void finalize_kernel(
    const float* __restrict__ x, const int* __restrict__ label,
    const double* __restrict__ partials, float* __restrict__ out, int B, int C)
{
    double acc = 0.0;
    for (int row = threadIdx.x; row < B; row += 1024) {
        double rs = 0.0;
        #pragma unroll
        for (int g = 0; g < GSPLIT; ++g) rs += partials[(size_t)row * GSPLIT + g];
        const double xy  = (double)x[(size_t)row * (size_t)C + label[row]];
        const double num = 64.0 * (xy - 0.35);
        const double exy = exp(64.0 * xy);
        const double sum_excl = rs - exy;          // fp64: cancellation-safe
        const double denom = exp(num) + sum_excl;
        acc += (num - log(denom)) / 64.0;
    }
    double total = block_reduce_d<16>(acc);
    if (threadIdx.x == 0) out[0] = (float)(-total / (double)B);
}

extern "C" void kernel_launch(void* const* d_in, const int* in_sizes, int n_in,
                              void* d_out, int out_size, void* d_ws, size_t ws_size,
                              hipStream_t stream) {
    const float* x     = (const float*)d_in[0];
    const int*   label = (const int*)d_in[1];
    const int B = in_sizes[1];
    const int C = in_sizes[0] / B;

    double* partials = (double*)d_ws;  // B * GSPLIT doubles = 32 KB scratch

    dim3 grid1(GSPLIT, B);
    partial_sum_kernel<<<grid1, NT, 0, stream>>>(x, partials, C);
    finalize_kernel<<<1, 1024, 0, stream>>>(x, label, partials, (float*)d_out, B, C);
}